// Round 3
// baseline (506.201 us; speedup 1.0000x reference)
//
#include <hip/hip_runtime.h>
#include <cstring>

// Scene splat, gather formulation v7.
// R1: 41M global atomics cap at 65 Gops/s -> gather inversion (994->519 us).
// R2/R4: ~308 us of dur_us is harness poison/restore (fixed floor); gather
//        ~165 us vs ~82 us traffic floor (180 MB cold read + 335 MB write).
// R5: channel-merge (5x MLP) was NEUTRAL -> not latency-bound on reads.
// R6 A/B: nt stores -> PLAIN stores (win). Writes terminate in L2/L3.
// R7: XCD-contiguous tile swizzle NEUTRAL -> L3 is die-shared; cross-XCD
//     duplicate fetch / drain fragmentation is not the lever.
// R8: tile reshape 64x64 -> 16x256 NEUTRAL -> write granularity not the
//     lever either. Gather time is invariant to store layout & scheduling.
// R9 (this): NONTEMPORAL READS. Theory: R6's win = output writes dying in
//   L3 before HBM drain (next poison overwrites them). But ~180 MB of
//   read-once patch traffic ALSO allocates in L3, evicting dirty output
//   lines mid-kernel -> forced in-kernel HBM drains, pattern-independent
//   ~2x efficiency loss (explains R7+R8 both neutral). Patch lines are
//   consumed by exactly one block (dup <10%) -> zero reuse value. nt loads
//   bypass cache allocation, preserving L3 for write residency.
//   Single-variable vs v6. Predict: gather 165 -> ~120-140, total ~435-455.
//   If neutral: all stream attributes exonerated -> harness floor, roofline.

typedef float vf4 __attribute__((ext_vector_type(4)));

constexpr int C  = 5;
constexpr int H  = 4096;
constexpr int W  = 4096;
constexpr int N  = 2000;
constexpr int PH = 64;
constexpr int PW = 64;

constexpr int TH = 16;                  // tile height
constexpr int TW = 256;                 // tile width
constexpr int TX = W / TW;              // 16 tiles per row
constexpr int TY = H / TH;              // 256 tile rows
constexpr int NTILES = TX * TY;         // 4096
constexpr int CAP    = 128;             // mean ~3.1 entries/tile; tail << 128

__global__ __launch_bounds__(256) void bin_patches(
    const int2* __restrict__ positions,
    int*        __restrict__ counts,    // [NTILES]
    int2*       __restrict__ lists)     // [NTILES][CAP] : {n, (py<<16)|px}
{
    int n = blockIdx.x * blockDim.x + threadIdx.x;
    if (n >= N) return;
    int2 p = positions[n];              // .x = row offset, .y = col offset
    int packed = (p.x << 16) | p.y;     // both < 4096, fit 16b
    int ty0 = p.x >> 4, ty1 = (p.x + PH - 1) >> 4;   // /TH : up to 5 tiles
    int tx0 = p.y >> 8, tx1 = (p.y + PW - 1) >> 8;   // /TW : 1-2 tiles
    for (int ty = ty0; ty <= ty1; ++ty)
        for (int tx = tx0; tx <= tx1; ++tx) {
            int tile = ty * TX + tx;
            int slot = atomicAdd(&counts[tile], 1);
            if (slot < CAP) lists[tile * CAP + slot] = make_int2(n, packed);
        }
}

__global__ __launch_bounds__(256) void gather_tiles(
    const float* __restrict__ patches,   // (N, C, PH, PW)
    const int*   __restrict__ counts,
    const int2*  __restrict__ lists,
    float*       __restrict__ out)       // (C, H, W)
{
    // R7 swizzle kept (neutral; harmless). NTILES % 8 == 0 -> bijective.
    int bid  = blockIdx.x;
    int tile = ((bid & 7) << 9) | (bid >> 3);

    int y0 = (tile >> 4) << 4;           // tile_y * TH
    int x0 = (tile & (TX - 1)) << 8;     // tile_x * TW
    int t  = threadIdx.x;
    int row  = t >> 4;                   // 0..15: thread's tile row
    int colb = (t & 15) << 2;            // base col; owns colb + 64*k, k=0..3

    vf4 acc[C][4] = {};                  // 80 VGPRs of accumulator

    int cnt = counts[tile];
    if (cnt > CAP) cnt = CAP;
    const int2* lst = lists + (size_t)tile * CAP;

    for (int i = 0; i < cnt; ++i) {
        int2 e = lst[i];                 // e.x = n, e.y = (py<<16)|px
        int py = e.y >> 16;
        int px = e.y & 0xffff;

        int pr = y0 - py + row;          // this thread's patch row
        if ((unsigned)pr >= (unsigned)PH) continue;

        const float* prow = patches + (size_t)e.x * (C * PH * PW) + pr * PW;
        int rx0 = x0 - px + colb;        // patch col of chunk k=0

        #pragma unroll
        for (int k = 0; k < 4; ++k) {
            int rxb = rx0 + 64 * k;
            if ((unsigned)rxb <= (unsigned)(PW - 4)) {
                #pragma unroll
                for (int c = 0; c < C; ++c) {     // 5 independent nt dwordx4s
                    const vf4* src = (const vf4*)(prow + c * (PH * PW) + rxb);
                    acc[c][k] += __builtin_nontemporal_load(src);
                }
            } else if (rxb > -4 && rxb < PW) {    // straddles patch x-edge
                #pragma unroll
                for (int j = 0; j < 4; ++j) {
                    int pxx = rxb + j;
                    if ((unsigned)pxx < (unsigned)PW) {
                        #pragma unroll
                        for (int c = 0; c < C; ++c)
                            acc[c][k][j] += __builtin_nontemporal_load(
                                prow + c * (PH * PW) + pxx);
                    }
                }
            }
        }
    }

    // Writeback: PLAIN stores (R6 win) — dirty lines die in L3 under the
    // next harness poison instead of draining to HBM in-kernel.
    #pragma unroll
    for (int c = 0; c < C; ++c) {
        float* orow = out + ((size_t)c * H + y0 + row) * W + x0;
        #pragma unroll
        for (int k = 0; k < 4; ++k) {
            *(vf4*)(orow + colb + 64 * k) = acc[c][k];
        }
    }
}

extern "C" void kernel_launch(void* const* d_in, const int* in_sizes, int n_in,
                              void* d_out, int out_size, void* d_ws, size_t ws_size,
                              hipStream_t stream) {
    const float* patches   = (const float*)d_in[0];
    const int2*  positions = (const int2*)d_in[1];
    float*       out       = (float*)d_out;

    int*  counts = (int*)d_ws;                       // NTILES ints
    int2* lists  = (int2*)(counts + NTILES);         // NTILES*CAP int2 (4 MB)

    (void)hipMemsetAsync(counts, 0, NTILES * sizeof(int), stream);

    bin_patches<<<(N + 255) / 256, 256, 0, stream>>>(positions, counts, lists);

    gather_tiles<<<NTILES, 256, 0, stream>>>(patches, counts, lists, out);
}

// Round 5
// 473.401 us; speedup vs baseline: 1.0693x; 1.0693x over previous
//
#include <hip/hip_runtime.h>
#include <cstring>

// Scene splat, gather formulation v8 (fused single kernel) — resubmit; R4's
// bench hit GPUAcquisitionTimeout (broker at capacity), kernel never ran.
// R1: 41M global atomics cap at 65 Gops/s -> gather inversion (994->519 us).
// R2/R4: ~308 us of dur_us is harness poison/restore (fixed floor); gather
//        ~165 us vs ~80 us traffic floor (164 MB cold read + 335 MB write).
// R5: channel-merge (5x MLP) NEUTRAL -> not read-latency-bound.
// R6 A/B: nt stores -> PLAIN stores (win). Writes die in L2/L3; next
//        harness poison overwrites dirty lines (full-line writes, no drain).
// R7: XCD-contiguous tile swizzle NEUTRAL -> L3 is die-shared.
// R8: tile reshape 64x64 -> 16x256 NEUTRAL -> write granularity not a lever.
// R9: NONTEMPORAL READS regressed +28 us -> split-boundary duplicate reads
//        (~50-80 MB) were hitting L3; nt refetched them from HBM. Reads
//        already cache-optimally. REVERTED.
// R10/R11 (this): fuse memset+bin+gather into ONE kernel. positions = 16 KB
//   -> every block scans all N=2000 positions from L2 (8 compares/thread)
//   and bins into LDS. Removes 2 launch serializations, the ws lists, and
//   the counts->lists->patches dependent global chain. Gather body /
//   geometry / store path byte-identical to v6. Predict 477 -> ~467-473.
//   If neutral, all levers (scheduling R7, layout R8, temporality R9,
//   pipeline R10) are exhausted -> declare practical roofline.

typedef float vf4 __attribute__((ext_vector_type(4)));

constexpr int C  = 5;
constexpr int H  = 4096;
constexpr int W  = 4096;
constexpr int N  = 2000;
constexpr int PH = 64;
constexpr int PW = 64;

constexpr int TH = 16;                  // tile height
constexpr int TW = 256;                 // tile width
constexpr int TX = W / TW;              // 16 tiles per row
constexpr int TY = H / TH;              // 256 tile rows
constexpr int NTILES = TX * TY;         // 4096
constexpr int LCAP   = 96;              // per-tile LDS list cap; mean ~3.1

__global__ __launch_bounds__(256) void splat_fused(
    const float* __restrict__ patches,    // (N, C, PH, PW)
    const int2*  __restrict__ positions,  // (N) {row, col}
    float*       __restrict__ out)        // (C, H, W)
{
    // R7 swizzle kept (neutral, harmless). NTILES % 8 == 0 -> bijective.
    int bid  = blockIdx.x;
    int tile = ((bid & 7) << 9) | (bid >> 3);

    int y0 = (tile >> 4) << 4;           // tile_y * TH
    int x0 = (tile & (TX - 1)) << 8;     // tile_x * TW
    int t  = threadIdx.x;
    int row  = t >> 4;                   // 0..15: thread's tile row
    int colb = (t & 15) << 2;            // base col; owns colb + 64*k, k=0..3

    // ---- in-kernel binning: scan all positions (16 KB, L2-broadcast) ----
    __shared__ int2 s_ent[LCAP];         // {n, (py<<16)|px}
    __shared__ int  s_cnt;
    if (t == 0) s_cnt = 0;
    __syncthreads();

    for (int n = t; n < N; n += 256) {
        int2 p = positions[n];           // .x = row offset, .y = col offset
        // patch rows [p.x, p.x+PH) vs tile rows [y0, y0+TH)
        // patch cols [p.y, p.y+PW) vs tile cols [x0, x0+TW)
        if (p.x < y0 + TH && p.x + PH > y0 &&
            p.y < x0 + TW && p.y + PW > x0) {
            int slot = atomicAdd(&s_cnt, 1);
            if (slot < LCAP)
                s_ent[slot] = make_int2(n, (p.x << 16) | p.y);
        }
    }
    __syncthreads();
    int cnt = s_cnt;
    if (cnt > LCAP) cnt = LCAP;

    // ---- gather: byte-identical body to v6 ----
    vf4 acc[C][4] = {};                  // 80 VGPRs of accumulator

    for (int i = 0; i < cnt; ++i) {
        int2 e = s_ent[i];               // e.x = n, e.y = (py<<16)|px
        int py = e.y >> 16;
        int px = e.y & 0xffff;

        int pr = y0 - py + row;          // this thread's patch row
        if ((unsigned)pr >= (unsigned)PH) continue;

        const float* prow = patches + (size_t)e.x * (C * PH * PW) + pr * PW;
        int rx0 = x0 - px + colb;        // patch col of chunk k=0

        #pragma unroll
        for (int k = 0; k < 4; ++k) {
            int rxb = rx0 + 64 * k;
            if ((unsigned)rxb <= (unsigned)(PW - 4)) {
                #pragma unroll
                for (int c = 0; c < C; ++c) {     // 5 independent dwordx4s
                    vf4 v;
                    __builtin_memcpy(&v, prow + c * (PH * PW) + rxb, sizeof(vf4));
                    acc[c][k] += v;
                }
            } else if (rxb > -4 && rxb < PW) {    // straddles patch x-edge
                #pragma unroll
                for (int j = 0; j < 4; ++j) {
                    int pxx = rxb + j;
                    if ((unsigned)pxx < (unsigned)PW) {
                        #pragma unroll
                        for (int c = 0; c < C; ++c)
                            acc[c][k][j] += prow[c * (PH * PW) + pxx];
                    }
                }
            }
        }
    }

    // Writeback: PLAIN stores (R6 win) — dirty lines die in L3 under the
    // next harness poison instead of draining to HBM in-kernel. Zero tiles
    // write zeros (replaces the full-frame memset).
    #pragma unroll
    for (int c = 0; c < C; ++c) {
        float* orow = out + ((size_t)c * H + y0 + row) * W + x0;
        #pragma unroll
        for (int k = 0; k < 4; ++k) {
            *(vf4*)(orow + colb + 64 * k) = acc[c][k];
        }
    }
}

extern "C" void kernel_launch(void* const* d_in, const int* in_sizes, int n_in,
                              void* d_out, int out_size, void* d_ws, size_t ws_size,
                              hipStream_t stream) {
    const float* patches   = (const float*)d_in[0];
    const int2*  positions = (const int2*)d_in[1];
    float*       out       = (float*)d_out;
    (void)d_ws; (void)ws_size;

    splat_fused<<<NTILES, 256, 0, stream>>>(patches, positions, out);
}

// Round 6
// 465.424 us; speedup vs baseline: 1.0876x; 1.0171x over previous
//
#include <hip/hip_runtime.h>
#include <cstring>

// Scene splat, gather formulation v9 (fused, occupancy-doubled).
// R1: 41M global atomics cap at 65 Gops/s -> gather inversion (994->519 us).
// R2/R4: ~308 us of dur_us is harness poison/restore (fixed floor); gather
//        ~165 us vs ~82 us traffic floor (184 MB cold read + 335 MB write).
// R5: channel-merge NEUTRAL. R6: plain stores WIN (die in L2/L3).
// R7: XCD swizzle NEUTRAL. R8: 64x64->16x256 reshape NEUTRAL (granularity
//     not a lever). R9: nt reads REGRESSED +28 (split dups were L3 hits).
// R10/R11: fused memset+bin+gather, single kernel: 477 -> 473 (win, as
//     predicted). absmax tightened to 1e-6.
// R12 (this): MLP/occupancy. m13's 6.29 TB/s is a float4 COPY (mixed R/W
//   stream) -> mixed traffic is NOT the ceiling; the 2x gap must be
//   memory-level parallelism. Little's law: 6.3 TB/s needs ~9 KB in flight
//   per CU at ~900cy cold latency. Entry loop serializes per-wave rounds
//   (in-order issue: next entry's loads wait on prior acc+= vmcnt), so
//   in-flight ~ waves/CU * burst duty. acc[5][4]=80 VGPR caps us at ~3-4
//   waves/SIMD -> ~8 KB in flight, just under the bar -> pattern-invariant
//   ~50% BW (consistent with R7/R8/R9 all neutral). Fix: halve tile to
//   16x128 (acc[5][2], ~-40 VGPR -> ~5 waves/SIMD), double grid to 8192
//   blocks (32/CU). Cost: x-split dup reads +20 MB (+3 us floor).
//   Predict: VGPR ~130->~90, Occupancy x1.5, total 473 -> ~435-450.
//   If neutral (>=470): revert to v8, declare practical roofline.

typedef float vf4 __attribute__((ext_vector_type(4)));

constexpr int C  = 5;
constexpr int H  = 4096;
constexpr int W  = 4096;
constexpr int N  = 2000;
constexpr int PH = 64;
constexpr int PW = 64;

constexpr int TH = 16;                  // tile height
constexpr int TW = 128;                 // tile width (was 256)
constexpr int TX = W / TW;              // 32 tiles per row
constexpr int TY = H / TH;              // 256 tile rows
constexpr int NTILES = TX * TY;         // 8192
constexpr int LCAP   = 96;              // mean ~1.8 entries/tile; tail << 96

__global__ __launch_bounds__(256) void splat_fused(
    const float* __restrict__ patches,    // (N, C, PH, PW)
    const int2*  __restrict__ positions,  // (N) {row, col}
    float*       __restrict__ out)        // (C, H, W)
{
    // XCD-contiguous swizzle (R7: neutral, harmless). NTILES % 8 == 0.
    int bid  = blockIdx.x;
    int tile = ((bid & 7) << 10) | (bid >> 3);

    int y0 = (tile >> 5) << 4;           // (tile / TX) * TH
    int x0 = (tile & (TX - 1)) << 7;     // (tile % TX) * TW
    int t  = threadIdx.x;
    int row  = t >> 4;                   // 0..15: thread's tile row
    int colb = (t & 15) << 2;            // base col; owns colb + 64*k, k=0..1

    // ---- in-kernel binning: scan all positions (16 KB, L2-broadcast) ----
    __shared__ int2 s_ent[LCAP];         // {n, (py<<16)|px}
    __shared__ int  s_cnt;
    if (t == 0) s_cnt = 0;
    __syncthreads();

    for (int n = t; n < N; n += 256) {
        int2 p = positions[n];           // .x = row offset, .y = col offset
        if (p.x < y0 + TH && p.x + PH > y0 &&
            p.y < x0 + TW && p.y + PW > x0) {
            int slot = atomicAdd(&s_cnt, 1);
            if (slot < LCAP)
                s_ent[slot] = make_int2(n, (p.x << 16) | p.y);
        }
    }
    __syncthreads();
    int cnt = s_cnt;
    if (cnt > LCAP) cnt = LCAP;

    // ---- gather: v6 body, k-range halved (acc[5][2] = 40 VGPR) ----
    vf4 acc[C][2] = {};

    for (int i = 0; i < cnt; ++i) {
        int2 e = s_ent[i];               // e.x = n, e.y = (py<<16)|px
        int py = e.y >> 16;
        int px = e.y & 0xffff;

        int pr = y0 - py + row;          // this thread's patch row
        if ((unsigned)pr >= (unsigned)PH) continue;

        const float* prow = patches + (size_t)e.x * (C * PH * PW) + pr * PW;
        int rx0 = x0 - px + colb;        // patch col of chunk k=0

        #pragma unroll
        for (int k = 0; k < 2; ++k) {
            int rxb = rx0 + 64 * k;
            if ((unsigned)rxb <= (unsigned)(PW - 4)) {
                #pragma unroll
                for (int c = 0; c < C; ++c) {     // 5 independent dwordx4s
                    vf4 v;
                    __builtin_memcpy(&v, prow + c * (PH * PW) + rxb, sizeof(vf4));
                    acc[c][k] += v;
                }
            } else if (rxb > -4 && rxb < PW) {    // straddles patch x-edge
                #pragma unroll
                for (int j = 0; j < 4; ++j) {
                    int pxx = rxb + j;
                    if ((unsigned)pxx < (unsigned)PW) {
                        #pragma unroll
                        for (int c = 0; c < C; ++c)
                            acc[c][k][j] += prow[c * (PH * PW) + pxx];
                    }
                }
            }
        }
    }

    // Writeback: PLAIN stores (R6 win); zero tiles write zeros (replaces
    // the full-frame memset).
    #pragma unroll
    for (int c = 0; c < C; ++c) {
        float* orow = out + ((size_t)c * H + y0 + row) * W + x0;
        #pragma unroll
        for (int k = 0; k < 2; ++k) {
            *(vf4*)(orow + colb + 64 * k) = acc[c][k];
        }
    }
}

extern "C" void kernel_launch(void* const* d_in, const int* in_sizes, int n_in,
                              void* d_out, int out_size, void* d_ws, size_t ws_size,
                              hipStream_t stream) {
    const float* patches   = (const float*)d_in[0];
    const int2*  positions = (const int2*)d_in[1];
    float*       out       = (float*)d_out;
    (void)d_ws; (void)ws_size;

    splat_fused<<<NTILES, 256, 0, stream>>>(patches, positions, out);
}